// Round 1
// baseline (2115.637 us; speedup 1.0000x reference)
//
#include <hip/hip_runtime.h>
#include <stdint.h>

#define T_    16
#define N_    2048
#define CAP_  96

__device__ inline float frcp(float x){
#if __has_builtin(__builtin_amdgcn_rcpf)
  return __builtin_amdgcn_rcpf(x);
#else
  return 1.0f / x;
#endif
}
__device__ inline float fsig(float x){ return frcp(1.0f + __expf(-x)); }
__device__ inline float ftanh(float x){ return 1.0f - 2.0f*frcp(1.0f + __expf(2.0f*x)); }

// ---------------------------------------------------------------- mask build
// m[t*N + (b*256+j)] = ego[b][t][j] != 0, with runtime dtype detection
__global__ __launch_bounds__(256) void k_mask(const uint8_t* __restrict__ ego_raw,
                                              float* __restrict__ m){
  __shared__ int s_int01, s_f01;
  const int tid = threadIdx.x;
  if (tid == 0){ s_int01 = 1; s_f01 = 1; }
  __syncthreads();
  const uint32_t* w = (const uint32_t*)ego_raw;
  int int01 = 1, f01 = 1;
  for (int i = tid; i < 8192; i += 256){
    uint32_t v = w[i];
    int01 &= (v <= 1u);
    f01   &= (v == 0u) || (v == 0x3F800000u);
  }
  if (!int01) atomicAnd(&s_int01, 0);
  if (!f01)   atomicAnd(&s_f01, 0);
  __syncthreads();
  const int mode = s_int01 ? 0 : (s_f01 ? 1 : 2); // 0:int32 1:f32 2:byte
  for (int i = tid; i < T_*N_; i += 256){
    int t = i >> 11, n = i & 2047, b = n >> 8, j = n & 255;
    int src = (b*T_ + t)*256 + j;
    float val;
    if (mode == 0)      val = (((const int32_t*)ego_raw)[src] != 0)   ? 1.f : 0.f;
    else if (mode == 1) val = (((const float*)ego_raw)[src]  != 0.f)  ? 1.f : 0.f;
    else                val = (ego_raw[src] != 0)                     ? 1.f : 0.f;
    m[i] = val;
  }
}

// ---------------------------------------------------------------- sparsify adj into CSC lists
__global__ __launch_bounds__(256) void k_sparsify(const float* __restrict__ adj,
                                                  int* __restrict__ cnt,
                                                  uint16_t* __restrict__ idx){
  const int bx = blockIdx.x;
  const int t = bx & 15;
  const int dchunk = (bx >> 4) & 7;
  const int schunk = bx >> 7;          // 0..15
  const int d = (dchunk << 8) + threadIdx.x;
  const int s0 = schunk << 7;
  const float* base = adj + ((size_t)t << 22);
  const int col = (t << 11) + d;
  #pragma unroll 4
  for (int i = 0; i < 128; i++){
    int s = s0 + i;
    float v = base[((size_t)s << 11) + d];
    if (v != 0.f){
      int pos = atomicAdd(&cnt[col], 1);
      if (pos < CAP_) idx[col*CAP_ + pos] = (uint16_t)s;
    }
  }
}

// ---------------------------------------------------------------- dinv
__global__ __launch_bounds__(256) void k_dinv(const int* __restrict__ cnt,
                                              const uint16_t* __restrict__ idx,
                                              const float* __restrict__ m,
                                              float* __restrict__ dinv){
  const int col = blockIdx.x*256 + threadIdx.x;
  int c = cnt[col]; if (c > CAP_) c = CAP_;
  const int tbase = col & ~2047;
  const uint16_t* lst = idx + col*CAP_;
  float s = 1.0f;                       // self-loop
  for (int i = 0; i < c; i++) s += m[tbase + lst[i]];
  dinv[col] = (m[col] > 0.5f) ? rsqrtf(s) : 0.f;
}

// ---------------------------------------------------------------- v1 = dinv * (x @ W1)
__global__ __launch_bounds__(256) void k_v1(const float* __restrict__ x,
                                            const float* __restrict__ W1,
                                            const float* __restrict__ dinv,
                                            float* __restrict__ v1){
  const int gid = blockIdx.x*256 + threadIdx.x;   // node*64 + h
  const int h = gid & 63, node = gid >> 6;
  v1[gid] = dinv[node] * (x[node*2]*W1[h] + x[node*2+1]*W1[64+h]);
}

// ---------------------------------------------------------------- sparse aggregation (both layers)
// mode 0: out = relu(dinv*acc + b)      (layer 1)
// mode 1: out = m * (dinv*acc + b)      (layer 2)
__global__ __launch_bounds__(256) void k_agg(const float* __restrict__ v,
                                             const int* __restrict__ cnt,
                                             const uint16_t* __restrict__ idx,
                                             const float* __restrict__ dinv,
                                             const float* __restrict__ m,
                                             const float* __restrict__ bias,
                                             float* __restrict__ out, int mode){
  const int col = blockIdx.x*4 + (threadIdx.x >> 6);
  const int lane = threadIdx.x & 63;
  int c = cnt[col]; if (c > CAP_) c = CAP_;
  const int tbase = col & ~2047;
  const uint16_t* lst = idx + col*CAP_;
  float acc = v[col*64 + lane];                    // self-loop term
  for (int i = 0; i < c; i++){
    int s = lst[i];
    acc += v[(tbase + s)*64 + lane];
  }
  float y = dinv[col]*acc + bias[lane];
  out[col*64 + lane] = (mode == 0) ? fmaxf(y, 0.f) : m[col]*y;
}

// ---------------------------------------------------------------- v2 = dinv * (h1 @ W2)
__global__ __launch_bounds__(256) void k_v2(const float* __restrict__ h1,
                                            const float* __restrict__ W2,
                                            const float* __restrict__ dinv,
                                            float* __restrict__ v2){
  const int gid = blockIdx.x*256 + threadIdx.x;   // node*64 + hp
  const int hp = gid & 63, node = gid >> 6;
  const float* row = h1 + node*64;
  float s = 0.f;
  #pragma unroll 8
  for (int h = 0; h < 64; h++) s += row[h]*W2[h*64 + hp];
  v2[gid] = dinv[node]*s;
}

// ---------------------------------------------------------------- P[n,t,j] = h2[t,n,:]@W_ih[j,:] + b_ih[j]+b_hh[j]
__global__ __launch_bounds__(256) void k_lstmpre(const float* __restrict__ h2,
                                                 const float* __restrict__ Wih,
                                                 const float* __restrict__ bih,
                                                 const float* __restrict__ bhh,
                                                 float* __restrict__ P){
  const int gid = blockIdx.x*256 + threadIdx.x;   // (n*16+t)*128 + j
  const int j = gid & 127;
  const int nt = gid >> 7;
  const int t = nt & 15, n = nt >> 4;
  const float* row = h2 + ((size_t)((t << 11) + n))*64;
  const float* wr = Wih + j*64;
  float s = bih[j] + bhh[j];
  #pragma unroll 8
  for (int h = 0; h < 64; h++) s += row[h]*wr[h];
  P[gid] = s;
}

// ---------------------------------------------------------------- LSTM scan: 16 chains, 1 wave each
// lane l: gates j_a=l, j_b=l+64  (l<32: i,g | l>=32: f,o)
__global__ __launch_bounds__(64) void k_lstm(const float* __restrict__ P,
                                             const float* __restrict__ Whh,
                                             const float* __restrict__ Wa,
                                             float* __restrict__ lstm_out,
                                             float* __restrict__ scores){
  const int t = blockIdx.x;       // chain 0..15
  const int l = threadIdx.x;      // 0..63
  float wa[32], wb[32];
  #pragma unroll
  for (int k = 0; k < 32; k++){ wa[k] = Whh[l*32 + k]; wb[k] = Whh[(l + 64)*32 + k]; }
  __shared__ float hbuf[32];
  if (l < 32) hbuf[l] = 0.f;
  float c = 0.f;
  const float wav = (l < 32) ? Wa[l] : 0.f;
  __syncthreads();
  for (int n = 0; n < N_; n++){
    const int base = (n*16 + t)*128;
    float pa = P[base + l];
    float pb = P[base + 64 + l];
    float da = 0.f, db = 0.f;
    const float4* h4 = (const float4*)hbuf;
    #pragma unroll
    for (int q = 0; q < 8; q++){
      float4 hv = h4[q];
      da = fmaf(wa[4*q+0], hv.x, da); db = fmaf(wb[4*q+0], hv.x, db);
      da = fmaf(wa[4*q+1], hv.y, da); db = fmaf(wb[4*q+1], hv.y, db);
      da = fmaf(wa[4*q+2], hv.z, da); db = fmaf(wb[4*q+2], hv.z, db);
      da = fmaf(wa[4*q+3], hv.w, da); db = fmaf(wb[4*q+3], hv.w, db);
    }
    float ga = pa + da, gb = pb + db;
    float act_a = fsig(ga);                              // i (l<32) | f (l>=32)
    float act_b = (l < 32) ? ftanh(gb) : fsig(gb);       // g (l<32) | o (l>=32)
    float xa = __shfl_xor(act_a, 32);
    float xb = __shfl_xor(act_b, 32);
    // lanes<32: i=act_a, g=act_b, f=xa, o=xb
    c = fmaf(xa, c, act_a*act_b);
    float th = ftanh(c);
    float hn = (l < 32) ? xb*th : 0.f;
    __syncthreads();
    if (l < 32){
      hbuf[l] = hn;
      lstm_out[((size_t)(t << 11) + n)*32 + l] = hn;
    }
    float sv = hn*wav;
    #pragma unroll
    for (int mm = 1; mm < 32; mm <<= 1) sv += __shfl_xor(sv, mm);
    if (l == 0) scores[(t << 11) + n] = sv;
    __syncthreads();
  }
}

// ---------------------------------------------------------------- softmax attention pool
__global__ __launch_bounds__(256) void k_attn(const float* __restrict__ scores,
                                              const float* __restrict__ lstm,
                                              float* __restrict__ out){
  const int gid = blockIdx.x*256 + threadIdx.x;   // n*32 + k
  const int k = gid & 31, n = gid >> 5;
  float sc[16]; float mx = -1e30f;
  #pragma unroll
  for (int t = 0; t < 16; t++){ float v = scores[(t << 11) + n]; sc[t] = v; mx = fmaxf(mx, v); }
  float sum = 0.f;
  #pragma unroll
  for (int t = 0; t < 16; t++){ float e = __expf(sc[t] - mx); sc[t] = e; sum += e; }
  const float inv = frcp(sum);
  float acc = 0.f;
  #pragma unroll
  for (int t = 0; t < 16; t++) acc += sc[t]*lstm[((size_t)(t << 11) + n)*32 + k];
  out[gid] = acc*inv;
}

// ---------------------------------------------------------------- launch
extern "C" void kernel_launch(void* const* d_in, const int* in_sizes, int n_in,
                              void* d_out, int out_size, void* d_ws, size_t ws_size,
                              hipStream_t stream){
  (void)in_sizes; (void)n_in; (void)out_size; (void)ws_size;
  const float*   x   = (const float*)d_in[0];
  const float*   adj = (const float*)d_in[1];
  const uint8_t* ego = (const uint8_t*)d_in[2];
  const float*   W1  = (const float*)d_in[3];
  const float*   b1  = (const float*)d_in[4];
  const float*   W2  = (const float*)d_in[5];
  const float*   b2  = (const float*)d_in[6];
  const float*   Wih = (const float*)d_in[7];
  const float*   Whh = (const float*)d_in[8];
  const float*   bih = (const float*)d_in[9];
  const float*   bhh = (const float*)d_in[10];
  const float*   Wa  = (const float*)d_in[11];
  // d_in[12] = ba: softmax is shift-invariant, unused
  float* out = (float*)d_out;
  char* ws = (char*)d_ws;

  float*    m      = (float*)(ws);                  // 128 KB
  float*    dinv   = (float*)(ws + 131072);         // 128 KB
  int*      cnt    = (int*)  (ws + 262144);         // 128 KB
  uint16_t* idx    = (uint16_t*)(ws + 393216);      // 6 MB
  float*    v      = (float*)(ws + 6684672);        // 8 MB   (v1 then v2)
  float*    h      = (float*)(ws + 15073280);       // 8 MB   (h1 then h2)
  float*    P      = (float*)(ws + 23461888);       // 16 MB
  float*    lstm   = (float*)(ws + 40239104);       // 4 MB
  float*    scores = (float*)(ws + 44433408);       // 128 KB

  hipMemsetAsync(cnt, 0, 131072, stream);
  k_mask    <<<1,     256, 0, stream>>>(ego, m);
  k_sparsify<<<2048,  256, 0, stream>>>(adj, cnt, idx);
  k_dinv    <<<128,   256, 0, stream>>>(cnt, idx, m, dinv);
  k_v1      <<<8192,  256, 0, stream>>>(x, W1, dinv, v);
  k_agg     <<<8192,  256, 0, stream>>>(v, cnt, idx, dinv, m, b1, h, 0);
  k_v2      <<<8192,  256, 0, stream>>>(h, W2, dinv, v);
  k_agg     <<<8192,  256, 0, stream>>>(v, cnt, idx, dinv, m, b2, h, 1);
  k_lstmpre <<<16384, 256, 0, stream>>>(h, Wih, bih, bhh, P);
  k_lstm    <<<16,    64,  0, stream>>>(P, Whh, Wa, lstm, scores);
  k_attn    <<<256,   256, 0, stream>>>(scores, lstm, out);
}

// Round 2
// 1743.728 us; speedup vs baseline: 1.2133x; 1.2133x over previous
//
#include <hip/hip_runtime.h>
#include <stdint.h>

#define T_    16
#define N_    2048
#define CAP_  96

__device__ inline float frcp(float x){
#if __has_builtin(__builtin_amdgcn_rcpf)
  return __builtin_amdgcn_rcpf(x);
#else
  return 1.0f / x;
#endif
}
__device__ inline float fsig(float x){ return frcp(1.0f + __expf(-x)); }
__device__ inline float rdlane(float v, int k){
  return __int_as_float(__builtin_amdgcn_readlane(__float_as_int(v), k));
}

// ---------------------------------------------------------------- mask build
// m[t*N + (b*256+j)] = ego[b][t][j] != 0, with runtime dtype detection
__global__ __launch_bounds__(256) void k_mask(const uint8_t* __restrict__ ego_raw,
                                              float* __restrict__ m){
  __shared__ int s_int01, s_f01;
  const int tid = threadIdx.x;
  if (tid == 0){ s_int01 = 1; s_f01 = 1; }
  __syncthreads();
  const uint32_t* w = (const uint32_t*)ego_raw;
  int int01 = 1, f01 = 1;
  for (int i = tid; i < 8192; i += 256){
    uint32_t v = w[i];
    int01 &= (v <= 1u);
    f01   &= (v == 0u) || (v == 0x3F800000u);
  }
  if (!int01) atomicAnd(&s_int01, 0);
  if (!f01)   atomicAnd(&s_f01, 0);
  __syncthreads();
  const int mode = s_int01 ? 0 : (s_f01 ? 1 : 2); // 0:int32 1:f32 2:byte
  for (int i = tid; i < T_*N_; i += 256){
    int t = i >> 11, n = i & 2047, b = n >> 8, j = n & 255;
    int src = (b*T_ + t)*256 + j;
    float val;
    if (mode == 0)      val = (((const int32_t*)ego_raw)[src] != 0)   ? 1.f : 0.f;
    else if (mode == 1) val = (((const float*)ego_raw)[src]  != 0.f)  ? 1.f : 0.f;
    else                val = (ego_raw[src] != 0)                     ? 1.f : 0.f;
    m[i] = val;
  }
}

// ---------------------------------------------------------------- sparsify adj into CSC lists
__global__ __launch_bounds__(256) void k_sparsify(const float* __restrict__ adj,
                                                  int* __restrict__ cnt,
                                                  uint16_t* __restrict__ idx){
  const int bx = blockIdx.x;
  const int t = bx & 15;
  const int dchunk = (bx >> 4) & 7;
  const int schunk = bx >> 7;          // 0..15
  const int d = (dchunk << 8) + threadIdx.x;
  const int s0 = schunk << 7;
  const float* base = adj + ((size_t)t << 22);
  const int col = (t << 11) + d;
  #pragma unroll 4
  for (int i = 0; i < 128; i++){
    int s = s0 + i;
    float v = base[((size_t)s << 11) + d];
    if (v != 0.f){
      int pos = atomicAdd(&cnt[col], 1);
      if (pos < CAP_) idx[col*CAP_ + pos] = (uint16_t)s;
    }
  }
}

// ---------------------------------------------------------------- dinv
__global__ __launch_bounds__(256) void k_dinv(const int* __restrict__ cnt,
                                              const uint16_t* __restrict__ idx,
                                              const float* __restrict__ m,
                                              float* __restrict__ dinv){
  const int col = blockIdx.x*256 + threadIdx.x;
  int c = cnt[col]; if (c > CAP_) c = CAP_;
  const int tbase = col & ~2047;
  const uint16_t* lst = idx + col*CAP_;
  float s = 1.0f;                       // self-loop
  for (int i = 0; i < c; i++) s += m[tbase + lst[i]];
  dinv[col] = (m[col] > 0.5f) ? rsqrtf(s) : 0.f;
}

// ---------------------------------------------------------------- v1 = dinv * (x @ W1)
__global__ __launch_bounds__(256) void k_v1(const float* __restrict__ x,
                                            const float* __restrict__ W1,
                                            const float* __restrict__ dinv,
                                            float* __restrict__ v1){
  const int gid = blockIdx.x*256 + threadIdx.x;   // node*64 + h
  const int h = gid & 63, node = gid >> 6;
  v1[gid] = dinv[node] * (x[node*2]*W1[h] + x[node*2+1]*W1[64+h]);
}

// ---------------------------------------------------------------- sparse aggregation (both layers)
// mode 0: out = relu(dinv*acc + b)      (layer 1)
// mode 1: out = m * (dinv*acc + b)      (layer 2)
__global__ __launch_bounds__(256) void k_agg(const float* __restrict__ v,
                                             const int* __restrict__ cnt,
                                             const uint16_t* __restrict__ idx,
                                             const float* __restrict__ dinv,
                                             const float* __restrict__ m,
                                             const float* __restrict__ bias,
                                             float* __restrict__ out, int mode){
  const int col = blockIdx.x*4 + (threadIdx.x >> 6);
  const int lane = threadIdx.x & 63;
  int c = cnt[col]; if (c > CAP_) c = CAP_;
  const int tbase = col & ~2047;
  const uint16_t* lst = idx + col*CAP_;
  float acc = v[col*64 + lane];                    // self-loop term
  for (int i = 0; i < c; i++){
    int s = lst[i];
    acc += v[(tbase + s)*64 + lane];
  }
  float y = dinv[col]*acc + bias[lane];
  out[col*64 + lane] = (mode == 0) ? fmaxf(y, 0.f) : m[col]*y;
}

// ---------------------------------------------------------------- v2 = dinv * (h1 @ W2)
__global__ __launch_bounds__(256) void k_v2(const float* __restrict__ h1,
                                            const float* __restrict__ W2,
                                            const float* __restrict__ dinv,
                                            float* __restrict__ v2){
  const int gid = blockIdx.x*256 + threadIdx.x;   // node*64 + hp
  const int hp = gid & 63, node = gid >> 6;
  const float* row = h1 + node*64;
  float s = 0.f;
  #pragma unroll 8
  for (int h = 0; h < 64; h++) s += row[h]*W2[h*64 + hp];
  v2[gid] = dinv[node]*s;
}

// ---------------------------------------------------------------- P2[t][n][j] = h2[t,n,:]@W_ih[j,:] + b_ih[j]+b_hh[j]
// Layout [t][n][128]: each LSTM chain t streams its P contiguously.
__global__ __launch_bounds__(256) void k_lstmpre(const float* __restrict__ h2,
                                                 const float* __restrict__ Wih,
                                                 const float* __restrict__ bih,
                                                 const float* __restrict__ bhh,
                                                 float* __restrict__ P2){
  const int gid = blockIdx.x*256 + threadIdx.x;   // ((t*2048+n)*128 + j)
  const int j = gid & 127;
  const int tn = gid >> 7;
  const int n = tn & 2047, t = tn >> 11;
  const float* row = h2 + ((size_t)((t << 11) + n))*64;
  const float* wr = Wih + j*64;
  float s = bih[j] + bhh[j];
  #pragma unroll 8
  for (int h = 0; h < 64; h++) s += row[h]*wr[h];
  P2[gid] = s;
}

// ---------------------------------------------------------------- LSTM scan: 16 chains, 1 wave each
// No barriers, no LDS: single wave is lockstep. All lanes redundantly keep
// c and h state for gate index j = l&31 (after the xor-32 exchange both
// half-waves hold all four activations). h broadcast via v_readlane (VALU,
// no DS latency). P prefetched 2 steps ahead in registers.
__global__ __launch_bounds__(64) void k_lstm(const float* __restrict__ P2,
                                             const float* __restrict__ Whh,
                                             float* __restrict__ lstm_out){
  const int t = blockIdx.x;       // chain 0..15
  const int l = threadIdx.x;      // 0..63
  // lane l: gate j_a = l (i for l<32, f for l>=32), j_b = l+64 (g | o)
  float wa[32], wb[32];
  #pragma unroll
  for (int k = 0; k < 32; k++){ wa[k] = Whh[l*32 + k]; wb[k] = Whh[(l + 64)*32 + k]; }
  const float* Pt = P2 + ((size_t)t << 11)*128;
  float* Lt = lstm_out + ((size_t)t << 11)*32;
  // branchless activation constants: tanh(x)=2*sig(2x)-1
  const bool lo = (l < 32);
  const float sc = lo ? -2.0f : -1.0f;   // act_b = ac*sig(-sc*... ) see below
  const float ac = lo ?  2.0f :  1.0f;
  const float bc = lo ? -1.0f :  0.0f;
  float c = 0.f;
  float hn = 0.f;                         // replicated h[l&31]
  // prefetch distance 2 (overread past n=2047 lands in the adjacent ws
  // region (lstm buffer) — loaded but never consumed; safe)
  float pa0 = Pt[l],        pb0 = Pt[64 + l];
  float pa1 = Pt[128 + l],  pb1 = Pt[192 + l];
  for (int n = 0; n < N_; n++){
    float pa = pa0, pb = pb0;
    pa0 = pa1; pb0 = pb1;
    const float* Pn = Pt + (n + 2)*128;
    pa1 = Pn[l]; pb1 = Pn[64 + l];
    float da0=0.f,da1=0.f,da2=0.f,da3=0.f;
    float db0=0.f,db1=0.f,db2=0.f,db3=0.f;
    #pragma unroll
    for (int k = 0; k < 32; k += 4){
      float h0 = rdlane(hn, k+0), h1 = rdlane(hn, k+1);
      float h2v = rdlane(hn, k+2), h3 = rdlane(hn, k+3);
      da0 = fmaf(wa[k+0], h0, da0); db0 = fmaf(wb[k+0], h0, db0);
      da1 = fmaf(wa[k+1], h1, da1); db1 = fmaf(wb[k+1], h1, db1);
      da2 = fmaf(wa[k+2], h2v, da2); db2 = fmaf(wb[k+2], h2v, db2);
      da3 = fmaf(wa[k+3], h3, da3); db3 = fmaf(wb[k+3], h3, db3);
    }
    float ga = pa + ((da0 + da1) + (da2 + da3));
    float gb = pb + ((db0 + db1) + (db2 + db3));
    float act_a = fsig(ga);                              // i (l<32) | f
    float sb = frcp(1.0f + __expf(gb * sc));
    float act_b = fmaf(ac, sb, bc);                      // tanh(g) | sig(o)
    float xa = __shfl_xor(act_a, 32);
    float xb = __shfl_xor(act_b, 32);
    float iv = lo ? act_a : xa;
    float fv = lo ? xa : act_a;
    float gv = lo ? act_b : xb;
    float ov = lo ? xb : act_b;
    c = fmaf(fv, c, iv*gv);
    float th = fmaf(2.0f, frcp(1.0f + __expf(-2.0f*c)), -1.0f);  // tanh(c)
    hn = ov*th;
    if (lo) Lt[n*32 + l] = hn;
  }
}

// ---------------------------------------------------------------- scores[t*2048+n] = lstm[t,n,:]@Wa
__global__ __launch_bounds__(256) void k_score(const float* __restrict__ lstm,
                                               const float* __restrict__ Wa,
                                               float* __restrict__ scores){
  const int gid = blockIdx.x*256 + threadIdx.x;   // t*2048 + n, 32768 total
  const float* row = lstm + (size_t)gid*32;
  float s = 0.f;
  #pragma unroll 8
  for (int k = 0; k < 32; k++) s += row[k]*Wa[k];
  scores[gid] = s;
}

// ---------------------------------------------------------------- softmax attention pool
__global__ __launch_bounds__(256) void k_attn(const float* __restrict__ scores,
                                              const float* __restrict__ lstm,
                                              float* __restrict__ out){
  const int gid = blockIdx.x*256 + threadIdx.x;   // n*32 + k
  const int k = gid & 31, n = gid >> 5;
  float sc[16]; float mx = -1e30f;
  #pragma unroll
  for (int t = 0; t < 16; t++){ float v = scores[(t << 11) + n]; sc[t] = v; mx = fmaxf(mx, v); }
  float sum = 0.f;
  #pragma unroll
  for (int t = 0; t < 16; t++){ float e = __expf(sc[t] - mx); sc[t] = e; sum += e; }
  const float inv = frcp(sum);
  float acc = 0.f;
  #pragma unroll
  for (int t = 0; t < 16; t++) acc += sc[t]*lstm[((size_t)(t << 11) + n)*32 + k];
  out[gid] = acc*inv;
}

// ---------------------------------------------------------------- launch
extern "C" void kernel_launch(void* const* d_in, const int* in_sizes, int n_in,
                              void* d_out, int out_size, void* d_ws, size_t ws_size,
                              hipStream_t stream){
  (void)in_sizes; (void)n_in; (void)out_size; (void)ws_size;
  const float*   x   = (const float*)d_in[0];
  const float*   adj = (const float*)d_in[1];
  const uint8_t* ego = (const uint8_t*)d_in[2];
  const float*   W1  = (const float*)d_in[3];
  const float*   b1  = (const float*)d_in[4];
  const float*   W2  = (const float*)d_in[5];
  const float*   b2  = (const float*)d_in[6];
  const float*   Wih = (const float*)d_in[7];
  const float*   Whh = (const float*)d_in[8];
  const float*   bih = (const float*)d_in[9];
  const float*   bhh = (const float*)d_in[10];
  const float*   Wa  = (const float*)d_in[11];
  // d_in[12] = ba: softmax is shift-invariant, unused
  float* out = (float*)d_out;
  char* ws = (char*)d_ws;

  float*    m      = (float*)(ws);                  // 128 KB
  float*    dinv   = (float*)(ws + 131072);         // 128 KB
  int*      cnt    = (int*)  (ws + 262144);         // 128 KB
  uint16_t* idx    = (uint16_t*)(ws + 393216);      // 6 MB
  float*    v      = (float*)(ws + 6684672);        // 8 MB   (v1 then v2)
  float*    h      = (float*)(ws + 15073280);       // 8 MB   (h1 then h2)
  float*    P      = (float*)(ws + 23461888);       // 16 MB
  float*    lstm   = (float*)(ws + 40239104);       // 4 MB
  float*    scores = (float*)(ws + 44433408);       // 128 KB

  hipMemsetAsync(cnt, 0, 131072, stream);
  k_mask    <<<1,     256, 0, stream>>>(ego, m);
  k_sparsify<<<2048,  256, 0, stream>>>(adj, cnt, idx);
  k_dinv    <<<128,   256, 0, stream>>>(cnt, idx, m, dinv);
  k_v1      <<<8192,  256, 0, stream>>>(x, W1, dinv, v);
  k_agg     <<<8192,  256, 0, stream>>>(v, cnt, idx, dinv, m, b1, h, 0);
  k_v2      <<<8192,  256, 0, stream>>>(h, W2, dinv, v);
  k_agg     <<<8192,  256, 0, stream>>>(v, cnt, idx, dinv, m, b2, h, 1);
  k_lstmpre <<<16384, 256, 0, stream>>>(h, Wih, bih, bhh, P);
  k_lstm    <<<16,    64,  0, stream>>>(P, Whh, lstm);
  k_score   <<<128,   256, 0, stream>>>(lstm, Wa, scores);
  k_attn    <<<256,   256, 0, stream>>>(scores, lstm, out);
}

// Round 3
// 1358.567 us; speedup vs baseline: 1.5573x; 1.2835x over previous
//
#include <hip/hip_runtime.h>
#include <stdint.h>

#define T_    16
#define N_    2048
#define CAP_  96

__device__ inline float frcp(float x){
#if __has_builtin(__builtin_amdgcn_rcpf)
  return __builtin_amdgcn_rcpf(x);
#else
  return 1.0f / x;
#endif
}
__device__ inline float fsig(float x){ return frcp(1.0f + __expf(-x)); }
__device__ inline float rdlane(float v, int k){
  return __int_as_float(__builtin_amdgcn_readlane(__float_as_int(v), k));
}

// ---------------------------------------------------------------- mask build + cnt zero
// m[t*N + (b*256+j)] = ego[b][t][j] != 0, with runtime dtype detection
__global__ __launch_bounds__(256) void k_mask(const uint8_t* __restrict__ ego_raw,
                                              float* __restrict__ m,
                                              int* __restrict__ cnt){
  __shared__ int s_int01, s_f01;
  const int tid = threadIdx.x;
  if (tid == 0){ s_int01 = 1; s_f01 = 1; }
  __syncthreads();
  const uint32_t* w = (const uint32_t*)ego_raw;
  int int01 = 1, f01 = 1;
  for (int i = tid; i < 8192; i += 256){
    uint32_t v = w[i];
    int01 &= (v <= 1u);
    f01   &= (v == 0u) || (v == 0x3F800000u);
  }
  if (!int01) atomicAnd(&s_int01, 0);
  if (!f01)   atomicAnd(&s_f01, 0);
  __syncthreads();
  const int mode = s_int01 ? 0 : (s_f01 ? 1 : 2); // 0:int32 1:f32 2:byte
  const int base = blockIdx.x * 2048;
  for (int q = tid; q < 2048; q += 256){
    int i = base + q;
    int t = i >> 11, n = i & 2047, b = n >> 8, j = n & 255;
    int src = (b*T_ + t)*256 + j;
    float val;
    if (mode == 0)      val = (((const int32_t*)ego_raw)[src] != 0)   ? 1.f : 0.f;
    else if (mode == 1) val = (((const float*)ego_raw)[src]  != 0.f)  ? 1.f : 0.f;
    else                val = (ego_raw[src] != 0)                     ? 1.f : 0.f;
    m[i] = val;
    cnt[i] = 0;
  }
}

// ---------------------------------------------------------------- sparsify adj into CSC lists
__global__ __launch_bounds__(256) void k_sparsify(const float* __restrict__ adj,
                                                  int* __restrict__ cnt,
                                                  uint16_t* __restrict__ idx){
  const int bx = blockIdx.x;
  const int t = bx & 15;
  const int dchunk = (bx >> 4) & 7;
  const int schunk = bx >> 7;          // 0..15
  const int d = (dchunk << 8) + threadIdx.x;
  const int s0 = schunk << 7;
  const float* base = adj + ((size_t)t << 22);
  const int col = (t << 11) + d;
  #pragma unroll 4
  for (int i = 0; i < 128; i++){
    int s = s0 + i;
    float v = base[((size_t)s << 11) + d];
    if (v != 0.f){
      int pos = atomicAdd(&cnt[col], 1);
      if (pos < CAP_) idx[col*CAP_ + pos] = (uint16_t)s;
    }
  }
}

// ---------------------------------------------------------------- dinv
__global__ __launch_bounds__(256) void k_dinv(const int* __restrict__ cnt,
                                              const uint16_t* __restrict__ idx,
                                              const float* __restrict__ m,
                                              float* __restrict__ dinv){
  const int col = blockIdx.x*256 + threadIdx.x;
  int c = cnt[col]; if (c > CAP_) c = CAP_;
  const int tbase = col & ~2047;
  const uint16_t* lst = idx + col*CAP_;
  float s = 1.0f;                       // self-loop
  for (int i = 0; i < c; i++) s += m[tbase + lst[i]];
  dinv[col] = (m[col] > 0.5f) ? rsqrtf(s) : 0.f;
}

// ---------------------------------------------------------------- layer 1 fused: h1 = relu(dinv*Σ dinv_s*(x_s@W1) + b1)
__global__ __launch_bounds__(256) void k_gcn1(const float* __restrict__ x,
                                              const float* __restrict__ W1,
                                              const float* __restrict__ b1,
                                              const int* __restrict__ cnt,
                                              const uint16_t* __restrict__ idx,
                                              const float* __restrict__ dinv,
                                              float* __restrict__ h1){
  const int col = blockIdx.x*4 + (threadIdx.x >> 6);
  const int lane = threadIdx.x & 63;
  int c = cnt[col]; if (c > CAP_) c = CAP_;
  const int tbase = col & ~2047;
  const uint16_t* lst = idx + col*CAP_;
  const float w1a = W1[lane], w1b = W1[64 + lane];
  const float2* x2 = (const float2*)x;
  float2 xs = x2[col];
  float acc = dinv[col]*(xs.x*w1a + xs.y*w1b);     // self-loop
  for (int i = 0; i < c; i++){
    int s = tbase + lst[i];
    float ds = dinv[s];
    float2 xv = x2[s];
    acc += ds*(xv.x*w1a + xv.y*w1b);
  }
  float y = dinv[col]*acc + b1[lane];
  h1[(size_t)col*64 + lane] = fmaxf(y, 0.f);
}

// ---------------------------------------------------------------- v2 = dinv * (h1 @ W2)
__global__ __launch_bounds__(256) void k_v2(const float* __restrict__ h1,
                                            const float* __restrict__ W2,
                                            const float* __restrict__ dinv,
                                            float* __restrict__ v2){
  const int gid = blockIdx.x*256 + threadIdx.x;   // node*64 + hp
  const int hp = gid & 63, node = gid >> 6;
  const float* row = h1 + (size_t)node*64;
  float s = 0.f;
  #pragma unroll 8
  for (int h = 0; h < 64; h++) s += row[h]*W2[h*64 + hp];
  v2[gid] = dinv[node]*s;
}

// ---------------------------------------------------------------- layer 2 aggregation: h2 = m * (dinv*Σ v2 + b2)
__global__ __launch_bounds__(256) void k_agg2(const float* __restrict__ v,
                                              const int* __restrict__ cnt,
                                              const uint16_t* __restrict__ idx,
                                              const float* __restrict__ dinv,
                                              const float* __restrict__ m,
                                              const float* __restrict__ b2,
                                              float* __restrict__ h2){
  const int col = blockIdx.x*4 + (threadIdx.x >> 6);
  const int lane = threadIdx.x & 63;
  int c = cnt[col]; if (c > CAP_) c = CAP_;
  const int tbase = col & ~2047;
  const uint16_t* lst = idx + col*CAP_;
  float acc = v[(size_t)col*64 + lane];            // self-loop
  for (int i = 0; i < c; i++){
    int s = lst[i];
    acc += v[((size_t)tbase + s)*64 + lane];
  }
  float y = dinv[col]*acc + b2[lane];
  h2[(size_t)col*64 + lane] = m[col]*y;
}

// ---------------------------------------------------------------- P4[(t*2048+n)*32+j] = {i,f,g,o} pre-activations
__global__ __launch_bounds__(256) void k_lstmpre(const float* __restrict__ h2,
                                                 const float* __restrict__ Wih,
                                                 const float* __restrict__ bih,
                                                 const float* __restrict__ bhh,
                                                 float* __restrict__ P4f){
  const int gid = blockIdx.x*256 + threadIdx.x;   // (t*2048+n)*128 + j128
  const int j128 = gid & 127;
  const int tn = gid >> 7;                        // t*2048 + n
  const float* row = h2 + (size_t)tn*64;
  const float* wr = Wih + j128*64;
  float s = bih[j128] + bhh[j128];
  #pragma unroll 8
  for (int h = 0; h < 64; h++) s += row[h]*wr[h];
  const int jj = j128 & 31, gate = j128 >> 5;
  P4f[(size_t)tn*128 + jj*4 + gate] = s;
}

// ---------------------------------------------------------------- LSTM scan: 16 chains, 1 wave each
// No DS ops at all: each lane computes ALL 4 gate dots for j=l&31 (both
// half-waves redundantly → hn,c replicated exactly), h broadcast via
// v_readlane. One dwordx4 P load per step (prefetch dist 2), full-wave
// contiguous store into stride-64 layout.
__global__ __launch_bounds__(64, 1) void k_lstm(const float* __restrict__ P4,
                                                const float* __restrict__ Whh,
                                                float* __restrict__ L64){
  const int t = blockIdx.x;       // chain 0..15
  const int l = threadIdx.x;      // 0..63
  const int j = l & 31;
  float wi[32], wf[32], wg[32], wo[32];
  #pragma unroll
  for (int k = 0; k < 32; k++){
    wi[k] = Whh[(     j)*32 + k];
    wf[k] = Whh[(32 + j)*32 + k];
    wg[k] = Whh[(64 + j)*32 + k];
    wo[k] = Whh[(96 + j)*32 + k];
  }
  const float4* Pt = (const float4*)P4 + (size_t)t*N_*32 + j;
  float* Lt = L64 + (size_t)t*N_*64;
  float c = 0.f, hn = 0.f;
  // prefetch distance 2; overread past n=2047 stays inside ws (after P4) — never consumed
  float4 p0 = Pt[0], p1 = Pt[32];
  for (int n = 0; n < N_; n++){
    float4 cur = p0; p0 = p1; p1 = Pt[(size_t)(n + 2)*32];
    float ai0=0.f, ai1=0.f, af0=0.f, af1=0.f;
    float ag0=0.f, ag1=0.f, ao0=0.f, ao1=0.f;
    #pragma unroll
    for (int k = 0; k < 32; k += 2){
      float h0 = rdlane(hn, k), h1 = rdlane(hn, k+1);
      ai0 = fmaf(wi[k  ], h0, ai0); ai1 = fmaf(wi[k+1], h1, ai1);
      af0 = fmaf(wf[k  ], h0, af0); af1 = fmaf(wf[k+1], h1, af1);
      ag0 = fmaf(wg[k  ], h0, ag0); ag1 = fmaf(wg[k+1], h1, ag1);
      ao0 = fmaf(wo[k  ], h0, ao0); ao1 = fmaf(wo[k+1], h1, ao1);
    }
    float gi = cur.x + (ai0 + ai1);
    float gf = cur.y + (af0 + af1);
    float gg = cur.z + (ag0 + ag1);
    float go = cur.w + (ao0 + ao1);
    float iv = fsig(gi);
    float fv = fsig(gf);
    float gv = fmaf(2.0f, fsig(2.0f*gg), -1.0f);   // tanh
    float ov = fsig(go);
    c = fmaf(fv, c, iv*gv);
    float th = fmaf(2.0f, fsig(2.0f*c), -1.0f);    // tanh(c)
    hn = ov*th;
    Lt[n*64 + l] = hn;                             // full-wave 256B store
  }
}

// ---------------------------------------------------------------- scores[t*2048+n] = lstm[t,n,:]@Wa
__global__ __launch_bounds__(256) void k_score(const float* __restrict__ L64,
                                               const float* __restrict__ Wa,
                                               float* __restrict__ scores){
  const int gid = blockIdx.x*256 + threadIdx.x;   // t*2048 + n, 32768 total
  const float* row = L64 + (size_t)gid*64;
  float s = 0.f;
  #pragma unroll 8
  for (int k = 0; k < 32; k++) s += row[k]*Wa[k];
  scores[gid] = s;
}

// ---------------------------------------------------------------- softmax attention pool
__global__ __launch_bounds__(256) void k_attn(const float* __restrict__ scores,
                                              const float* __restrict__ L64,
                                              float* __restrict__ out){
  const int gid = blockIdx.x*256 + threadIdx.x;   // n*32 + k
  const int k = gid & 31, n = gid >> 5;
  float sc[16]; float mx = -1e30f;
  #pragma unroll
  for (int t = 0; t < 16; t++){ float v = scores[(t << 11) + n]; sc[t] = v; mx = fmaxf(mx, v); }
  float sum = 0.f;
  #pragma unroll
  for (int t = 0; t < 16; t++){ float e = __expf(sc[t] - mx); sc[t] = e; sum += e; }
  const float inv = frcp(sum);
  float acc = 0.f;
  #pragma unroll
  for (int t = 0; t < 16; t++) acc += sc[t]*L64[((size_t)((t << 11) + n))*64 + k];
  out[gid] = acc*inv;
}

// ---------------------------------------------------------------- launch
extern "C" void kernel_launch(void* const* d_in, const int* in_sizes, int n_in,
                              void* d_out, int out_size, void* d_ws, size_t ws_size,
                              hipStream_t stream){
  (void)in_sizes; (void)n_in; (void)out_size; (void)ws_size;
  const float*   x   = (const float*)d_in[0];
  const float*   adj = (const float*)d_in[1];
  const uint8_t* ego = (const uint8_t*)d_in[2];
  const float*   W1  = (const float*)d_in[3];
  const float*   b1  = (const float*)d_in[4];
  const float*   W2  = (const float*)d_in[5];
  const float*   b2  = (const float*)d_in[6];
  const float*   Wih = (const float*)d_in[7];
  const float*   Whh = (const float*)d_in[8];
  const float*   bih = (const float*)d_in[9];
  const float*   bhh = (const float*)d_in[10];
  const float*   Wa  = (const float*)d_in[11];
  // d_in[12] = ba: softmax is shift-invariant, unused
  float* out = (float*)d_out;
  char* ws = (char*)d_ws;

  float*    m      = (float*)(ws);                  // 128 KB
  float*    dinv   = (float*)(ws + 131072);         // 128 KB
  int*      cnt    = (int*)  (ws + 262144);         // 128 KB
  uint16_t* idx    = (uint16_t*)(ws + 393216);      // 6 MB
  float*    v      = (float*)(ws + 6684672);        // 8 MB   (v2; later reused as L64)
  float*    h      = (float*)(ws + 15073280);       // 8 MB   (h1 then h2; later scores)
  float*    P4     = (float*)(ws + 23461888);       // 16 MB
  float*    L64    = v;                             // v dead after k_agg2
  float*    scores = h;                             // h dead after k_lstmpre

  k_mask    <<<16,    256, 0, stream>>>(ego, m, cnt);
  k_sparsify<<<2048,  256, 0, stream>>>(adj, cnt, idx);
  k_dinv    <<<128,   256, 0, stream>>>(cnt, idx, m, dinv);
  k_gcn1    <<<8192,  256, 0, stream>>>(x, W1, b1, cnt, idx, dinv, h);
  k_v2      <<<8192,  256, 0, stream>>>(h, W2, dinv, v);
  k_agg2    <<<8192,  256, 0, stream>>>(v, cnt, idx, dinv, m, b2, h);
  k_lstmpre <<<16384, 256, 0, stream>>>(h, Wih, bih, bhh, P4);
  k_lstm    <<<16,    64,  0, stream>>>(P4, Whh, L64);
  k_score   <<<128,   256, 0, stream>>>(L64, Wa, scores);
  k_attn    <<<256,   256, 0, stream>>>(scores, L64, out);
}